// Round 1
// baseline (332.951 us; speedup 1.0000x reference)
//
#include <hip/hip_runtime.h>
#include <hip/hip_bf16.h>

constexpr int NB   = 2;
constexpr int LL   = 512;
constexpr int LLP  = 516;          // padded s_exp row stride (516 % 32 != 0 -> no 4-way conflicts)
constexpr int FF   = 128;
constexpr int CC   = 64;
constexpr int HH   = 12;
constexpr int DD   = 16;
constexpr int HD   = HH * DD;      // 192
constexpr int FEAT = HH*CC + HH*DD + HH*7;  // 1044
constexpr float INFV   = 100000.0f;
constexpr float SCALEF = 0.57735026918962576f;   // sqrt(1/3)
constexpr float SQ29H  = 0.23570226039551584f;   // sqrt(2/9)/2

// ---------------- kernel 1: q/k/v projections, 4 rows per block ----------------
// W (294 KB) streamed via LDS once per block -> amortized over 4 rows
// (L2 traffic for W: 301 MB -> 75 MB). vT stores vectorized to float4 over rows.
__global__ __launch_bounds__(192) void qkv_kernel(
    const float* __restrict__ xg, const float* __restrict__ Wq,
    const float* __restrict__ Wk, const float* __restrict__ Wv,
    float* __restrict__ q_ws, float* __restrict__ kT4, float* __restrict__ vT)
{
    const int b = blockIdx.x;          // 256 blocks, rows b*4 .. b*4+3 (never straddle n)
    const int t = threadIdx.x;         // 192
    __shared__ __align__(16) float sx[4*FF];
    __shared__ __align__(16) float sw[3*HD*20];   // 45 KB

    for (int o = t; o < 4*FF; o += 192) sx[o] = xg[(size_t)b*4*FF + o];

    float aq[4] = {0.f,0.f,0.f,0.f};
    float ak[4] = {0.f,0.f,0.f,0.f};
    float av[4] = {0.f,0.f,0.f,0.f};

    for (int ft = 0; ft < 8; ++ft) {
        __syncthreads();
        #pragma unroll
        for (int m = 0; m < 3; ++m) {
            const float* W = (m == 0) ? Wq : ((m == 1) ? Wk : Wv);
            #pragma unroll
            for (int p = 0; p < 4; ++p) {
                const int r = (t >> 2) + 48*p, q = t & 3;
                float4 v = *(const float4*)(W + (size_t)r*FF + ft*16 + q*4);
                *(float4*)&sw[m*3840 + r*20 + q*4] = v;
            }
        }
        __syncthreads();
        const float* wq = &sw[0*3840 + t*20];
        const float* wk = &sw[1*3840 + t*20];
        const float* wv = &sw[2*3840 + t*20];
        #pragma unroll
        for (int f4 = 0; f4 < 4; ++f4) {
            float4 a = *(const float4*)&wq[f4*4];
            float4 bq = *(const float4*)&wk[f4*4];
            float4 cq = *(const float4*)&wv[f4*4];
            #pragma unroll
            for (int r = 0; r < 4; ++r) {
                float4 xv = *(const float4*)&sx[r*FF + ft*16 + f4*4];   // broadcast
                aq[r] += xv.x*a.x  + xv.y*a.y  + xv.z*a.z  + xv.w*a.w;
                ak[r] += xv.x*bq.x + xv.y*bq.y + xv.z*bq.z + xv.w*bq.w;
                av[r] += xv.x*cq.x + xv.y*cq.y + xv.z*cq.z + xv.w*cq.w;
            }
        }
    }
    const int n = (b*4) >> 9, i0 = (b*4) & 511;
    #pragma unroll
    for (int r = 0; r < 4; ++r) {
        const int row = b*4 + r, i = i0 + r;
        q_ws[(size_t)row*HD + t] = aq[r];
        kT4[(((size_t)n*48 + (t >> 2))*LL + i)*4 + (t & 3)] = ak[r];
    }
    *(float4*)&vT[((size_t)n*HD + t)*LL + i0] = make_float4(av[0], av[1], av[2], av[3]);
}

// ---------------- kernel 2: fused attention, 512 threads/block ----------------
// LDS cut 43.5 KB -> ~33.3 KB so 4 blocks/CU fit (grid = 256 CU x 4 exactly):
//  - 2b partials: 4x768 f32 buffer replaced by 768 f32 + LDS atomicAdd
//  - phase 4 partials: LDS buffer replaced by quad shuffle reduce
// s_exp rows padded to 516 floats -> phase-2a ds_read_b128 conflicts gone.
__global__ __launch_bounds__(512, 8) void attn_kernel(
    const float* __restrict__ Rg, const float* __restrict__ tg, const float* __restrict__ pg,
    const float* __restrict__ xg, const float* __restrict__ zg, const int* __restrict__ maskg,
    const float* __restrict__ Wpbg, const float* __restrict__ gammag,
    const float* __restrict__ Woutg, const float* __restrict__ boutg,
    const float* __restrict__ lnwg, const float* __restrict__ lnbg,
    const float* __restrict__ q_ws, const float* __restrict__ kT4, const float* __restrict__ vT,
    float* __restrict__ outg)
{
    const int row = blockIdx.x;          // n*LL + i
    const int n = row >> 9;
    const int tid = threadIdx.x;

    __shared__ __align__(16) float s_exp[HH*LLP];  // 24.2 KB  exp(logits), h-major, padded
    __shared__ __align__(16) float s_wacc[HH*CC];  // 3 KB  Wpb (phase1) then 2b accumulators
    __shared__ __align__(16) float s_q[HD];
    __shared__ __align__(16) float s_x[FF];
    __shared__ __align__(16) float s_y[FF];
    __shared__ __align__(16) float s_f[FEAT];
    __shared__ float s_aggr[36];
    __shared__ float s_inv[HH];
    __shared__ float s_coef[HH];
    __shared__ float s_geo[15];   // p_i[3], t[3], R[9]
    __shared__ float s_red[2];

    if (tid < FF) s_x[tid] = xg[(size_t)row*FF + tid];
    if (tid >= 128 && tid < 128 + HD) s_q[tid-128] = q_ws[(size_t)row*HD + (tid-128)];
    for (int o = tid; o < HH*CC; o += 512) s_wacc[o] = Wpbg[o];   // wpb staged
    if (tid >= 320 && tid < 332) {
        float g = gammag[tid-320];
        float gamma = log1pf(__expf(fminf(g, 80.0f)));   // softplus
        s_coef[tid-320] = -gamma * SQ29H;
    }
    if (tid >= 332 && tid < 335) s_geo[tid-332] = pg[(size_t)row*3 + (tid-332)];
    if (tid >= 335 && tid < 338) s_geo[3 + tid-335] = tg[(size_t)row*3 + (tid-335)];
    if (tid >= 338 && tid < 347) s_geo[6 + tid-338] = Rg[(size_t)row*9 + (tid-338)];
    const int mi = maskg[row];   // block-uniform
    __syncthreads();

    if (mi) {
        // ---- phase 1: exp(logits), one j per thread; acc[12], z read ONCE ----
        {
            const int j = tid;
            float acc[HH];
            #pragma unroll
            for (int h = 0; h < HH; ++h) acc[h] = 0.f;

            // z . Wpb : z chunk consumed immediately against LDS broadcasts
            const float* zr = zg + ((size_t)row*LL + j)*CC;
            #pragma unroll
            for (int c4 = 0; c4 < CC/4; ++c4) {
                float4 zv = *(const float4*)(zr + c4*4);
                #pragma unroll
                for (int h = 0; h < HH; ++h) {
                    float4 w = *(const float4*)&s_wacc[h*CC + c4*4];   // broadcast
                    acc[h] += zv.x*w.x + zv.y*w.y + zv.z*w.z + zv.w*w.w;
                }
            }
            // q . k : kT4 -> one coalesced dwordx4 per hd4
            const float* kb = kT4 + ((size_t)(n*48)*LL + j)*4;
            #pragma unroll
            for (int hd4 = 0; hd4 < HD/4; ++hd4) {
                float4 q4 = *(const float4*)&s_q[hd4*4];
                float4 k4 = *(const float4*)(kb + (size_t)hd4*LL*4);
                acc[hd4 >> 2] += q4.x*k4.x + q4.y*k4.y + q4.z*k4.z + q4.w*k4.w;
            }
            const float* pj = pg + ((size_t)n*LL + j)*3;
            float e0 = s_geo[0]-pj[0];
            float e1 = s_geo[1]-pj[1];
            float e2 = s_geo[2]-pj[2];
            float d2 = e0*e0 + e1*e1 + e2*e2;
            const float sub = maskg[n*LL + j] ? 0.0f : INFV;
            #pragma unroll
            for (int h = 0; h < HH; ++h) {
                float lg = (acc[h] + d2*s_coef[h]) * SCALEF - sub;
                s_exp[h*LLP + j] = __expf(fminf(lg, 80.0f));
            }
        }
        __syncthreads();

        // ---- per-head sums -> reciprocals; also zero 2b accumulators ----
        {
            const int wv = tid >> 6, lane = tid & 63;
            for (int h = wv; h < HH; h += 8) {
                float s = 0.f;
                #pragma unroll
                for (int r = 0; r < 8; ++r) s += s_exp[h*LLP + lane + (r<<6)];
                #pragma unroll
                for (int off = 32; off > 0; off >>= 1) s += __shfl_xor(s, off, 64);
                if (lane == 0) s_inv[h] = 1.0f / fmaxf(s, 1e-30f);
            }
            if (tid < 384) *(float2*)&s_wacc[tid*2] = make_float2(0.f, 0.f);
        }
        __syncthreads();

        // ---- phases 2a + 2b CONCURRENT on disjoint waves ----
        {
            const int wv = tid >> 6, lane = tid & 63;
            if (wv < 4) {
                // 2b: feat_p2n partials; wave = j-chunk of 128, lane = c
                const int c = lane, q4v = wv;
                float acc[HH];
                #pragma unroll
                for (int h = 0; h < HH; ++h) acc[h] = 0.f;
                const float* zb = zg + ((size_t)row*LL + q4v*128)*CC + c;
                const float* ep = s_exp + q4v*128;
                #pragma unroll 2
                for (int jj = 0; jj < 128; jj += 4) {
                    float z0 = zb[(size_t)(jj+0)*CC];
                    float z1 = zb[(size_t)(jj+1)*CC];
                    float z2 = zb[(size_t)(jj+2)*CC];
                    float z3 = zb[(size_t)(jj+3)*CC];
                    #pragma unroll
                    for (int h = 0; h < HH; ++h) {
                        float4 e = *(const float4*)&ep[h*LLP + jj];   // broadcast b128
                        acc[h] += e.x*z0 + e.y*z1 + e.z*z2 + e.w*z3;
                    }
                }
                #pragma unroll
                for (int h = 0; h < HH; ++h) atomicAdd(&s_wacc[h*64 + c], acc[h]);
            } else if (tid < 448) {
                // 2a: feat_node, hd = tid-256, full-j float4 (vT)
                const int hd = tid - 256;
                const float* vb = vT + ((size_t)n*HD + hd)*LL;
                const float* ep = s_exp + (hd >> 4)*LLP;
                float a = 0.f;
                #pragma unroll 4
                for (int j4 = 0; j4 < 128; ++j4) {
                    float4 vv = *(const float4*)(vb + j4*4);
                    float4 ev = *(const float4*)(ep + j4*4);
                    a += vv.x*ev.x + vv.y*ev.y + vv.z*ev.z + vv.w*ev.w;
                }
                s_f[768 + hd] = a * s_inv[hd >> 4];
            } else {
                // alpha . p_CB: 36 outputs on wave 7
                const int o = tid - 448;
                if (o < 36) {
                    const int h = o / 3, ax = o - h*3;
                    const float* pb = pg + (size_t)n*LL*3 + ax;
                    const float* ep = s_exp + h*LLP;
                    float a = 0.f;
                    #pragma unroll 4
                    for (int j = 0; j < LL; ++j) a += ep[j] * pb[(size_t)j*3];
                    s_aggr[o] = a * s_inv[h];
                }
            }
        }
        __syncthreads();

        // ---- 2b scale + phase 3 ----
        for (int o = tid; o < 768; o += 512)
            s_f[o] = s_wacc[o] * s_inv[o >> 6];
        if (tid >= 500) {
            const int h = tid - 500;   // 0..11
            float m0 = s_aggr[h*3+0] - s_geo[3];
            float m1 = s_aggr[h*3+1] - s_geo[4];
            float m2 = s_aggr[h*3+2] - s_geo[5];
            const float* Rm = &s_geo[6];           // local_i = sum_j R[j][i]*m[j]
            float l0 = Rm[0]*m0 + Rm[3]*m1 + Rm[6]*m2;
            float l1 = Rm[1]*m0 + Rm[4]*m1 + Rm[7]*m2;
            float l2 = Rm[2]*m0 + Rm[5]*m1 + Rm[8]*m2;
            float dist = sqrtf(l0*l0 + l1*l1 + l2*l2);
            float idn = 1.0f/(dist + 1e-4f);
            s_f[960 + h*3+0] = l0; s_f[960 + h*3+1] = l1; s_f[960 + h*3+2] = l2;
            s_f[996 + h] = dist;
            s_f[1008 + h*3+0] = l0*idn; s_f[1008 + h*3+1] = l1*idn; s_f[1008 + h*3+2] = l2*idn;
        }
        __syncthreads();

        // ---- phase 4: output projection; quad of lanes per f (coalesced Wout) ----
        {
            const int f = tid >> 2, q4 = tid & 3;
            const float* wr = Woutg + (size_t)f * FEAT;
            float acc = 0.f;
            for (int kk = q4*4; kk < FEAT; kk += 16) {
                float4 fv  = *(const float4*)&s_f[kk];
                float4 wvv = *(const float4*)(wr + kk);
                acc += fv.x*wvv.x + fv.y*wvv.y + fv.z*wvv.z + fv.w*wvv.w;
            }
            acc += __shfl_xor(acc, 1, 64);
            acc += __shfl_xor(acc, 2, 64);
            if (q4 == 0) s_y[f] = s_x[f] + boutg[f] + acc;
        }
    } else {
        if (tid < FF) s_y[tid] = s_x[tid];
    }
    __syncthreads();

    // ---- LayerNorm ----
    if (tid < 64) {
        float a = s_y[tid], b = s_y[tid + 64];
        float s1 = a + b, s2 = a*a + b*b;
        #pragma unroll
        for (int off = 32; off > 0; off >>= 1) {
            s1 += __shfl_xor(s1, off, 64);
            s2 += __shfl_xor(s2, off, 64);
        }
        if (tid == 0) { s_red[0] = s1; s_red[1] = s2; }
    }
    __syncthreads();
    if (tid < FF) {
        float mu  = s_red[0] * (1.0f/FF);
        float var = s_red[1] * (1.0f/FF) - mu*mu;
        float vv = (s_y[tid] - mu) * rsqrtf(fmaxf(var, 0.0f) + 1e-5f);
        vv = vv * lnwg[tid] + lnbg[tid];
        outg[(size_t)row*FF + tid] = vv;
    }
}

extern "C" void kernel_launch(void* const* d_in, const int* in_sizes, int n_in,
                              void* d_out, int out_size, void* d_ws, size_t ws_size,
                              hipStream_t stream) {
    const float* Rg    = (const float*)d_in[0];
    const float* tg    = (const float*)d_in[1];
    const float* pg    = (const float*)d_in[2];
    const float* xg    = (const float*)d_in[3];
    const float* zg    = (const float*)d_in[4];
    const int*   maskg = (const int*)d_in[5];
    const float* Wq    = (const float*)d_in[6];
    const float* Wk    = (const float*)d_in[7];
    const float* Wv    = (const float*)d_in[8];
    const float* Wpb   = (const float*)d_in[9];
    const float* gam   = (const float*)d_in[10];
    const float* Wout  = (const float*)d_in[11];
    const float* bout  = (const float*)d_in[12];
    const float* lnw   = (const float*)d_in[13];
    const float* lnb   = (const float*)d_in[14];
    float* outp = (float*)d_out;

    float* q_ws = (float*)d_ws;
    float* kT4  = q_ws + (size_t)NB*LL*HD;
    float* vT   = kT4  + (size_t)NB*LL*HD;

    qkv_kernel<<<NB*LL/4, HD, 0, stream>>>(xg, Wq, Wk, Wv, q_ws, kT4, vT);
    attn_kernel<<<NB*LL, 512, 0, stream>>>(Rg, tg, pg, xg, zg, maskg,
                                           Wpb, gam, Wout, bout, lnw, lnb,
                                           q_ws, kT4, vT, outp);
}

// Round 2
// 303.958 us; speedup vs baseline: 1.0954x; 1.0954x over previous
//
#include <hip/hip_runtime.h>
#include <hip/hip_bf16.h>

constexpr int NB   = 2;
constexpr int LL   = 512;
constexpr int LLP  = 516;          // padded s_exp row stride (kills 4-way b128 conflicts)
constexpr int FF   = 128;
constexpr int CC   = 64;
constexpr int HH   = 12;
constexpr int DD   = 16;
constexpr int HD   = HH * DD;      // 192
constexpr int FEAT = HH*CC + HH*DD + HH*7;  // 1044
constexpr float INFV   = 100000.0f;
constexpr float SCALEF = 0.57735026918962576f;   // sqrt(1/3)
constexpr float SQ29H  = 0.23570226039551584f;   // sqrt(2/9)/2

// ---------------- kernel 0: active-row compaction ----------------
// mask is random 0/1 -> ~half the attn blocks are trivial. Without compaction,
// heavy blocks land Binomial(4,1/2) per CU -> ~6% of CUs get 4 heavy blocks and
// run a half-throughput tail. row_map lists active rows first so every CU gets
// exactly ~2 heavy blocks.
__global__ void compact_kernel(const int* __restrict__ maskg, int* __restrict__ row_map)
{
    const int tid = threadIdx.x;               // 1024 threads = NB*LL
    const int lane = tid & 63, wv = tid >> 6;  // 16 waves
    __shared__ int s_cnt[16];
    __shared__ int s_off[16];
    __shared__ int s_tot;
    const int m = maskg[tid] ? 1 : 0;
    unsigned long long b = __ballot(m);
    const int pre = __popcll(b & ((1ull << lane) - 1ull));
    if (lane == 0) s_cnt[wv] = __popcll(b);
    __syncthreads();
    if (tid == 0) {
        int s = 0;
        for (int w = 0; w < 16; ++w) { s_off[w] = s; s += s_cnt[w]; }
        s_tot = s;
    }
    __syncthreads();
    const int nact = s_off[wv] + pre;          // actives strictly before tid
    if (m) row_map[nact] = tid;
    else   row_map[s_tot + (tid - nact)] = tid;
}

// ---------------- kernel 1: q/k/v projections, 4 rows per block ----------------
__global__ __launch_bounds__(192) void qkv_kernel(
    const float* __restrict__ xg, const float* __restrict__ Wq,
    const float* __restrict__ Wk, const float* __restrict__ Wv,
    float* __restrict__ q_ws, float* __restrict__ kT4, float* __restrict__ vT)
{
    const int b = blockIdx.x;          // 256 blocks, rows b*4 .. b*4+3 (never straddle n)
    const int t = threadIdx.x;         // 192
    __shared__ __align__(16) float sx[4*FF];
    __shared__ __align__(16) float sw[3*HD*20];   // 45 KB

    for (int o = t; o < 4*FF; o += 192) sx[o] = xg[(size_t)b*4*FF + o];

    float aq[4] = {0.f,0.f,0.f,0.f};
    float ak[4] = {0.f,0.f,0.f,0.f};
    float av[4] = {0.f,0.f,0.f,0.f};

    for (int ft = 0; ft < 8; ++ft) {
        __syncthreads();
        #pragma unroll
        for (int m = 0; m < 3; ++m) {
            const float* W = (m == 0) ? Wq : ((m == 1) ? Wk : Wv);
            #pragma unroll
            for (int p = 0; p < 4; ++p) {
                const int r = (t >> 2) + 48*p, q = t & 3;
                float4 v = *(const float4*)(W + (size_t)r*FF + ft*16 + q*4);
                *(float4*)&sw[m*3840 + r*20 + q*4] = v;
            }
        }
        __syncthreads();
        const float* wq = &sw[0*3840 + t*20];
        const float* wk = &sw[1*3840 + t*20];
        const float* wv = &sw[2*3840 + t*20];
        #pragma unroll
        for (int f4 = 0; f4 < 4; ++f4) {
            float4 a  = *(const float4*)&wq[f4*4];
            float4 bq = *(const float4*)&wk[f4*4];
            float4 cq = *(const float4*)&wv[f4*4];
            #pragma unroll
            for (int r = 0; r < 4; ++r) {
                float4 xv = *(const float4*)&sx[r*FF + ft*16 + f4*4];   // broadcast
                aq[r] += xv.x*a.x  + xv.y*a.y  + xv.z*a.z  + xv.w*a.w;
                ak[r] += xv.x*bq.x + xv.y*bq.y + xv.z*bq.z + xv.w*bq.w;
                av[r] += xv.x*cq.x + xv.y*cq.y + xv.z*cq.z + xv.w*cq.w;
            }
        }
    }
    const int n = (b*4) >> 9, i0 = (b*4) & 511;
    #pragma unroll
    for (int r = 0; r < 4; ++r) {
        const int row = b*4 + r, i = i0 + r;
        q_ws[(size_t)row*HD + t] = aq[r];
        kT4[(((size_t)n*48 + (t >> 2))*LL + i)*4 + (t & 3)] = ak[r];
    }
    *(float4*)&vT[((size_t)n*HD + t)*LL + i0] = make_float4(av[0], av[1], av[2], av[3]);
}

// ---------------- kernel 2: fused attention (round-0 structure + padding + row_map) ----
__global__ __launch_bounds__(512, 2) void attn_kernel(
    const float* __restrict__ Rg, const float* __restrict__ tg, const float* __restrict__ pg,
    const float* __restrict__ xg, const float* __restrict__ zg, const int* __restrict__ maskg,
    const float* __restrict__ Wpbg, const float* __restrict__ gammag,
    const float* __restrict__ Woutg, const float* __restrict__ boutg,
    const float* __restrict__ lnwg, const float* __restrict__ lnbg,
    const float* __restrict__ q_ws, const float* __restrict__ kT4, const float* __restrict__ vT,
    const int* __restrict__ row_map, float* __restrict__ outg)
{
    const int row = row_map[blockIdx.x];  // load-balanced: active rows first
    const int n = row >> 9;
    const int tid = threadIdx.x;

    __shared__ __align__(16) float s_exp[HH*LLP];  // 24.2 KB  exp(logits), h-major, padded
    __shared__ __align__(16) float s_big[4*768];   // 12 KB  wpb (phase1) / 2b partials / p4 partials
    __shared__ __align__(16) float s_q[HD];
    __shared__ __align__(16) float s_x[FF];
    __shared__ __align__(16) float s_y[FF];
    __shared__ __align__(16) float s_f[FEAT];
    __shared__ float s_aggr[36];
    __shared__ float s_inv[HH];
    __shared__ float s_coef[HH];
    __shared__ float s_geo[15];   // p_i[3], t[3], R[9]
    __shared__ float s_red[2];

    if (tid < FF) s_x[tid] = xg[(size_t)row*FF + tid];
    if (tid >= 128 && tid < 128 + HD) s_q[tid-128] = q_ws[(size_t)row*HD + (tid-128)];
    for (int o = tid; o < HH*CC; o += 512) s_big[o] = Wpbg[o];   // wpb staged in s_big
    if (tid >= 320 && tid < 332) {
        float g = gammag[tid-320];
        float gamma = log1pf(__expf(fminf(g, 80.0f)));   // softplus
        s_coef[tid-320] = -gamma * SQ29H;
    }
    if (tid >= 332 && tid < 335) s_geo[tid-332] = pg[(size_t)row*3 + (tid-332)];
    if (tid >= 335 && tid < 338) s_geo[3 + tid-335] = tg[(size_t)row*3 + (tid-335)];
    if (tid >= 338 && tid < 347) s_geo[6 + tid-338] = Rg[(size_t)row*9 + (tid-338)];
    const int mi = maskg[row];   // block-uniform
    __syncthreads();

    if (mi) {
        // ---- phase 1: exp(logits), one j per thread; acc[12], z read ONCE ----
        {
            const int j = tid;
            float acc[HH];
            #pragma unroll
            for (int h = 0; h < HH; ++h) acc[h] = 0.f;

            // z . Wpb : z chunk consumed immediately against LDS broadcasts
            const float* zr = zg + ((size_t)row*LL + j)*CC;
            #pragma unroll
            for (int c4 = 0; c4 < CC/4; ++c4) {
                float4 zv = *(const float4*)(zr + c4*4);
                #pragma unroll
                for (int h = 0; h < HH; ++h) {
                    float4 w = *(const float4*)&s_big[h*CC + c4*4];   // broadcast
                    acc[h] += zv.x*w.x + zv.y*w.y + zv.z*w.z + zv.w*w.w;
                }
            }
            // q . k : kT4 -> one coalesced dwordx4 per hd4
            const float* kb = kT4 + ((size_t)(n*48)*LL + j)*4;
            #pragma unroll
            for (int hd4 = 0; hd4 < HD/4; ++hd4) {
                float4 q4 = *(const float4*)&s_q[hd4*4];
                float4 k4 = *(const float4*)(kb + (size_t)hd4*LL*4);
                acc[hd4 >> 2] += q4.x*k4.x + q4.y*k4.y + q4.z*k4.z + q4.w*k4.w;
            }
            const float* pj = pg + ((size_t)n*LL + j)*3;
            float e0 = s_geo[0]-pj[0];
            float e1 = s_geo[1]-pj[1];
            float e2 = s_geo[2]-pj[2];
            float d2 = e0*e0 + e1*e1 + e2*e2;
            const float sub = maskg[n*LL + j] ? 0.0f : INFV;
            #pragma unroll
            for (int h = 0; h < HH; ++h) {
                float lg = (acc[h] + d2*s_coef[h]) * SCALEF - sub;
                s_exp[h*LLP + j] = __expf(fminf(lg, 80.0f));
            }
        }
        __syncthreads();

        // ---- per-head sums -> reciprocals ----
        {
            const int wv = tid >> 6, lane = tid & 63;
            for (int h = wv; h < HH; h += 8) {
                float s = 0.f;
                #pragma unroll
                for (int r = 0; r < 8; ++r) s += s_exp[h*LLP + lane + (r<<6)];
                #pragma unroll
                for (int off = 32; off > 0; off >>= 1) s += __shfl_xor(s, off, 64);
                if (lane == 0) s_inv[h] = 1.0f / fmaxf(s, 1e-30f);
            }
        }
        __syncthreads();

        // ---- phases 2a + 2b CONCURRENT on disjoint waves ----
        {
            const int wv = tid >> 6, lane = tid & 63;
            if (wv < 4) {
                // 2b: feat_p2n partials; wave = j-chunk of 128, lane = c (scalar ep broadcast)
                const int c = lane, q4v = wv;
                float acc[HH];
                #pragma unroll
                for (int h = 0; h < HH; ++h) acc[h] = 0.f;
                const float* zb = zg + ((size_t)row*LL + q4v*128)*CC + c;
                const float* ep = s_exp + q4v*128;
                #pragma unroll 2
                for (int jj = 0; jj < 128; ++jj) {
                    float zv = zb[(size_t)jj*CC];
                    #pragma unroll
                    for (int h = 0; h < HH; ++h) acc[h] += ep[h*LLP + jj] * zv;
                }
                #pragma unroll
                for (int h = 0; h < HH; ++h) s_big[q4v*768 + h*64 + c] = acc[h];
            } else if (tid < 448) {
                // 2a: feat_node, hd = tid-256, full-j float4 (vT)
                const int hd = tid - 256;
                const float* vb = vT + ((size_t)n*HD + hd)*LL;
                const float* ep = s_exp + (hd >> 4)*LLP;
                float a = 0.f;
                #pragma unroll 2
                for (int j4 = 0; j4 < 128; ++j4) {
                    float4 vv = *(const float4*)(vb + j4*4);
                    float4 ev = *(const float4*)(ep + j4*4);
                    a += vv.x*ev.x + vv.y*ev.y + vv.z*ev.z + vv.w*ev.w;
                }
                s_f[768 + hd] = a * s_inv[hd >> 4];
            } else {
                // alpha . p_CB: 36 outputs on wave 7
                const int o = tid - 448;
                if (o < 36) {
                    const int h = o / 3, ax = o - h*3;
                    const float* pb = pg + (size_t)n*LL*3 + ax;
                    const float* ep = s_exp + h*LLP;
                    float a = 0.f;
                    #pragma unroll 4
                    for (int j = 0; j < LL; ++j) a += ep[j] * pb[(size_t)j*3];
                    s_aggr[o] = a * s_inv[h];
                }
            }
        }
        __syncthreads();

        // ---- 2b reduce + phase 3 ----
        for (int o = tid; o < 768; o += 512)
            s_f[o] = (s_big[o] + s_big[768+o] + s_big[1536+o] + s_big[2304+o]) * s_inv[o >> 6];
        if (tid >= 500) {
            const int h = tid - 500;   // 0..11
            float m0 = s_aggr[h*3+0] - s_geo[3];
            float m1 = s_aggr[h*3+1] - s_geo[4];
            float m2 = s_aggr[h*3+2] - s_geo[5];
            const float* Rm = &s_geo[6];           // local_i = sum_j R[j][i]*m[j]
            float l0 = Rm[0]*m0 + Rm[3]*m1 + Rm[6]*m2;
            float l1 = Rm[1]*m0 + Rm[4]*m1 + Rm[7]*m2;
            float l2 = Rm[2]*m0 + Rm[5]*m1 + Rm[8]*m2;
            float dist = sqrtf(l0*l0 + l1*l1 + l2*l2);
            float idn = 1.0f/(dist + 1e-4f);
            s_f[960 + h*3+0] = l0; s_f[960 + h*3+1] = l1; s_f[960 + h*3+2] = l2;
            s_f[996 + h] = dist;
            s_f[1008 + h*3+0] = l0*idn; s_f[1008 + h*3+1] = l1*idn; s_f[1008 + h*3+2] = l2*idn;
        }
        __syncthreads();

        // ---- phase 4: output projection, 4 quarters per f ----
        {
            const int f = tid & 127, q4 = tid >> 7;
            const float* wr = Woutg + (size_t)f * FEAT;
            float acc = 0.f;
            for (int kk = q4*4; kk < FEAT; kk += 16) {
                float4 fv  = *(const float4*)&s_f[kk];
                float4 wvv = *(const float4*)(wr + kk);
                acc += fv.x*wvv.x + fv.y*wvv.y + fv.z*wvv.z + fv.w*wvv.w;
            }
            s_big[q4*FF + f] = acc;
        }
        __syncthreads();
        if (tid < FF)
            s_y[tid] = s_x[tid] + boutg[tid]
                     + s_big[tid] + s_big[FF + tid] + s_big[2*FF + tid] + s_big[3*FF + tid];
    } else {
        if (tid < FF) s_y[tid] = s_x[tid];
    }
    __syncthreads();

    // ---- LayerNorm ----
    if (tid < 64) {
        float a = s_y[tid], b = s_y[tid + 64];
        float s1 = a + b, s2 = a*a + b*b;
        #pragma unroll
        for (int off = 32; off > 0; off >>= 1) {
            s1 += __shfl_xor(s1, off, 64);
            s2 += __shfl_xor(s2, off, 64);
        }
        if (tid == 0) { s_red[0] = s1; s_red[1] = s2; }
    }
    __syncthreads();
    if (tid < FF) {
        float mu  = s_red[0] * (1.0f/FF);
        float var = s_red[1] * (1.0f/FF) - mu*mu;
        float vv = (s_y[tid] - mu) * rsqrtf(fmaxf(var, 0.0f) + 1e-5f);
        vv = vv * lnwg[tid] + lnbg[tid];
        outg[(size_t)row*FF + tid] = vv;
    }
}

extern "C" void kernel_launch(void* const* d_in, const int* in_sizes, int n_in,
                              void* d_out, int out_size, void* d_ws, size_t ws_size,
                              hipStream_t stream) {
    const float* Rg    = (const float*)d_in[0];
    const float* tg    = (const float*)d_in[1];
    const float* pg    = (const float*)d_in[2];
    const float* xg    = (const float*)d_in[3];
    const float* zg    = (const float*)d_in[4];
    const int*   maskg = (const int*)d_in[5];
    const float* Wq    = (const float*)d_in[6];
    const float* Wk    = (const float*)d_in[7];
    const float* Wv    = (const float*)d_in[8];
    const float* Wpb   = (const float*)d_in[9];
    const float* gam   = (const float*)d_in[10];
    const float* Wout  = (const float*)d_in[11];
    const float* bout  = (const float*)d_in[12];
    const float* lnw   = (const float*)d_in[13];
    const float* lnb   = (const float*)d_in[14];
    float* outp = (float*)d_out;

    float* q_ws = (float*)d_ws;
    float* kT4  = q_ws + (size_t)NB*LL*HD;
    float* vT   = kT4  + (size_t)NB*LL*HD;
    int*   row_map = (int*)(vT + (size_t)NB*LL*HD);

    compact_kernel<<<1, NB*LL, 0, stream>>>(maskg, row_map);
    qkv_kernel<<<NB*LL/4, HD, 0, stream>>>(xg, Wq, Wk, Wv, q_ws, kT4, vT);
    attn_kernel<<<NB*LL, 512, 0, stream>>>(Rg, tg, pg, xg, zg, maskg,
                                           Wpb, gam, Wout, bout, lnw, lnb,
                                           q_ws, kT4, vT, row_map, outp);
}

// Round 3
// 294.909 us; speedup vs baseline: 1.1290x; 1.0307x over previous
//
#include <hip/hip_runtime.h>
#include <hip/hip_bf16.h>

constexpr int NB   = 2;
constexpr int LL   = 512;
constexpr int LLP  = 516;          // padded s_exp row stride (kills 4-way b128 conflicts)
constexpr int FF   = 128;
constexpr int CC   = 64;
constexpr int HH   = 12;
constexpr int DD   = 16;
constexpr int HD   = HH * DD;      // 192
constexpr int FEAT = HH*CC + HH*DD + HH*7;  // 1044
constexpr float INFV   = 100000.0f;
constexpr float SCALEF = 0.57735026918962576f;   // sqrt(1/3)
constexpr float SQ29H  = 0.23570226039551584f;   // sqrt(2/9)/2

// ---------------- kernel 0: active-row compaction ----------------
__global__ void compact_kernel(const int* __restrict__ maskg, int* __restrict__ row_map)
{
    const int tid = threadIdx.x;               // 1024 threads = NB*LL
    const int lane = tid & 63, wv = tid >> 6;  // 16 waves
    __shared__ int s_cnt[16];
    __shared__ int s_off[16];
    __shared__ int s_tot;
    const int m = maskg[tid] ? 1 : 0;
    unsigned long long b = __ballot(m);
    const int pre = __popcll(b & ((1ull << lane) - 1ull));
    if (lane == 0) s_cnt[wv] = __popcll(b);
    __syncthreads();
    if (tid == 0) {
        int s = 0;
        for (int w = 0; w < 16; ++w) { s_off[w] = s; s += s_cnt[w]; }
        s_tot = s;
    }
    __syncthreads();
    const int nact = s_off[wv] + pre;          // actives strictly before tid
    if (m) row_map[nact] = tid;
    else   row_map[s_tot + (tid - nact)] = tid;
}

// ---------------- kernel 1: q/k/v projections, 4 rows per block ----------------
__global__ __launch_bounds__(192) void qkv_kernel(
    const float* __restrict__ xg, const float* __restrict__ Wq,
    const float* __restrict__ Wk, const float* __restrict__ Wv,
    float* __restrict__ q_ws, float* __restrict__ kT4, float* __restrict__ vT)
{
    const int b = blockIdx.x;          // 256 blocks, rows b*4 .. b*4+3 (never straddle n)
    const int t = threadIdx.x;         // 192
    __shared__ __align__(16) float sx[4*FF];
    __shared__ __align__(16) float sw[3*HD*20];   // 45 KB

    for (int o = t; o < 4*FF; o += 192) sx[o] = xg[(size_t)b*4*FF + o];

    float aq[4] = {0.f,0.f,0.f,0.f};
    float ak[4] = {0.f,0.f,0.f,0.f};
    float av[4] = {0.f,0.f,0.f,0.f};

    for (int ft = 0; ft < 8; ++ft) {
        __syncthreads();
        #pragma unroll
        for (int m = 0; m < 3; ++m) {
            const float* W = (m == 0) ? Wq : ((m == 1) ? Wk : Wv);
            #pragma unroll
            for (int p = 0; p < 4; ++p) {
                const int r = (t >> 2) + 48*p, q = t & 3;
                float4 v = *(const float4*)(W + (size_t)r*FF + ft*16 + q*4);
                *(float4*)&sw[m*3840 + r*20 + q*4] = v;
            }
        }
        __syncthreads();
        const float* wq = &sw[0*3840 + t*20];
        const float* wk = &sw[1*3840 + t*20];
        const float* wv = &sw[2*3840 + t*20];
        #pragma unroll
        for (int f4 = 0; f4 < 4; ++f4) {
            float4 a  = *(const float4*)&wq[f4*4];
            float4 bq = *(const float4*)&wk[f4*4];
            float4 cq = *(const float4*)&wv[f4*4];
            #pragma unroll
            for (int r = 0; r < 4; ++r) {
                float4 xv = *(const float4*)&sx[r*FF + ft*16 + f4*4];   // broadcast
                aq[r] += xv.x*a.x  + xv.y*a.y  + xv.z*a.z  + xv.w*a.w;
                ak[r] += xv.x*bq.x + xv.y*bq.y + xv.z*bq.z + xv.w*bq.w;
                av[r] += xv.x*cq.x + xv.y*cq.y + xv.z*cq.z + xv.w*cq.w;
            }
        }
    }
    const int n = (b*4) >> 9, i0 = (b*4) & 511;
    #pragma unroll
    for (int r = 0; r < 4; ++r) {
        const int row = b*4 + r, i = i0 + r;
        q_ws[(size_t)row*HD + t] = aq[r];
        kT4[(((size_t)n*48 + (t >> 2))*LL + i)*4 + (t & 3)] = ak[r];
    }
    *(float4*)&vT[((size_t)n*HD + t)*LL + i0] = make_float4(av[0], av[1], av[2], av[3]);
}

// ---------------- kernel 2: fused attention (deep load batching) ----------------
__global__ __launch_bounds__(512, 2) void attn_kernel(
    const float* __restrict__ Rg, const float* __restrict__ tg, const float* __restrict__ pg,
    const float* __restrict__ xg, const float* __restrict__ zg, const int* __restrict__ maskg,
    const float* __restrict__ Wpbg, const float* __restrict__ gammag,
    const float* __restrict__ Woutg, const float* __restrict__ boutg,
    const float* __restrict__ lnwg, const float* __restrict__ lnbg,
    const float* __restrict__ q_ws, const float* __restrict__ kT4, const float* __restrict__ vT,
    const int* __restrict__ row_map, float* __restrict__ outg)
{
    const int row = row_map[blockIdx.x];  // load-balanced: active rows first
    const int n = row >> 9;
    const int tid = threadIdx.x;

    __shared__ __align__(16) float s_exp[HH*LLP];  // 24.2 KB  exp(logits), h-major, padded
    __shared__ __align__(16) float s_big[4*768];   // 12 KB  wpb (phase1) / 2b partials / p4 partials
    __shared__ __align__(16) float s_p[3*LL];      // 6 KB   p_CB for this n (phase1 + aggr)
    __shared__ __align__(16) float s_q[HD];
    __shared__ __align__(16) float s_x[FF];
    __shared__ __align__(16) float s_y[FF];
    __shared__ __align__(16) float s_f[FEAT];
    __shared__ float s_aggr[36];
    __shared__ float s_inv[HH];
    __shared__ float s_coef[HH];
    __shared__ float s_geo[15];   // p_i[3], t[3], R[9]
    __shared__ float s_red[2];

    if (tid < FF) s_x[tid] = xg[(size_t)row*FF + tid];
    if (tid >= 128 && tid < 128 + HD) s_q[tid-128] = q_ws[(size_t)row*HD + (tid-128)];
    for (int o = tid; o < HH*CC; o += 512) s_big[o] = Wpbg[o];   // wpb staged in s_big
    for (int o = tid; o < 3*LL; o += 512) s_p[o] = pg[(size_t)n*3*LL + o];
    if (tid >= 320 && tid < 332) {
        float g = gammag[tid-320];
        float gamma = log1pf(__expf(fminf(g, 80.0f)));   // softplus
        s_coef[tid-320] = -gamma * SQ29H;
    }
    if (tid >= 332 && tid < 335) s_geo[tid-332] = pg[(size_t)row*3 + (tid-332)];
    if (tid >= 335 && tid < 338) s_geo[3 + tid-335] = tg[(size_t)row*3 + (tid-335)];
    if (tid >= 338 && tid < 347) s_geo[6 + tid-338] = Rg[(size_t)row*9 + (tid-338)];
    const int mi = maskg[row];   // block-uniform
    __syncthreads();

    if (mi) {
        // ---- phase 1: exp(logits), one j per thread; all z in regs before FMA ----
        {
            const int j = tid;
            float acc[HH];
            #pragma unroll
            for (int h = 0; h < HH; ++h) acc[h] = 0.f;

            // z row -> 16 float4 regs (single vmcnt wait), then FMA vs LDS broadcasts
            const float* zr = zg + ((size_t)row*LL + j)*CC;
            float4 zv[16];
            #pragma unroll
            for (int c4 = 0; c4 < 16; ++c4) zv[c4] = ((const float4*)zr)[c4];
            #pragma unroll
            for (int c4 = 0; c4 < 16; ++c4) {
                #pragma unroll
                for (int h = 0; h < HH; ++h) {
                    float4 w = *(const float4*)&s_big[h*CC + c4*4];   // broadcast
                    acc[h] += zv[c4].x*w.x + zv[c4].y*w.y + zv[c4].z*w.z + zv[c4].w*w.w;
                }
            }
            // q . k : kT4, 8 loads in flight per group
            const float* kb = kT4 + ((size_t)(n*48)*LL + j)*4;
            #pragma unroll
            for (int g = 0; g < 6; ++g) {
                float4 kv[8];
                #pragma unroll
                for (int u = 0; u < 8; ++u)
                    kv[u] = *(const float4*)(kb + (size_t)(g*8+u)*LL*4);
                #pragma unroll
                for (int u = 0; u < 8; ++u) {
                    const int hd4 = g*8+u;
                    float4 q4v = *(const float4*)&s_q[hd4*4];
                    acc[hd4 >> 2] += q4v.x*kv[u].x + q4v.y*kv[u].y + q4v.z*kv[u].z + q4v.w*kv[u].w;
                }
            }
            float e0 = s_geo[0]-s_p[j*3+0];
            float e1 = s_geo[1]-s_p[j*3+1];
            float e2 = s_geo[2]-s_p[j*3+2];
            float d2 = e0*e0 + e1*e1 + e2*e2;
            const float sub = maskg[n*LL + j] ? 0.0f : INFV;
            #pragma unroll
            for (int h = 0; h < HH; ++h) {
                float lg = (acc[h] + d2*s_coef[h]) * SCALEF - sub;
                s_exp[h*LLP + j] = __expf(fminf(lg, 80.0f));
            }
        }
        __syncthreads();

        // ---- per-head sums -> reciprocals ----
        {
            const int wv = tid >> 6, lane = tid & 63;
            for (int h = wv; h < HH; h += 8) {
                float s = 0.f;
                #pragma unroll
                for (int r = 0; r < 8; ++r) s += s_exp[h*LLP + lane + (r<<6)];
                #pragma unroll
                for (int off = 32; off > 0; off >>= 1) s += __shfl_xor(s, off, 64);
                if (lane == 0) s_inv[h] = 1.0f / fmaxf(s, 1e-30f);
            }
        }
        __syncthreads();

        // ---- phases 2a + 2b CONCURRENT on disjoint waves ----
        {
            const int wv = tid >> 6, lane = tid & 63;
            if (wv < 4) {
                // 2b: feat_p2n partials; 8 z loads in flight, float4 ep broadcasts
                const int c = lane, q4v = wv;
                float acc[HH];
                #pragma unroll
                for (int h = 0; h < HH; ++h) acc[h] = 0.f;
                const float* zb = zg + ((size_t)row*LL + q4v*128)*CC + c;
                const float* ep = s_exp + q4v*128;
                #pragma unroll 2
                for (int jj = 0; jj < 128; jj += 8) {
                    float z0 = zb[(size_t)(jj+0)*CC];
                    float z1 = zb[(size_t)(jj+1)*CC];
                    float z2 = zb[(size_t)(jj+2)*CC];
                    float z3 = zb[(size_t)(jj+3)*CC];
                    float z4 = zb[(size_t)(jj+4)*CC];
                    float z5 = zb[(size_t)(jj+5)*CC];
                    float z6 = zb[(size_t)(jj+6)*CC];
                    float z7 = zb[(size_t)(jj+7)*CC];
                    #pragma unroll
                    for (int h = 0; h < HH; ++h) {
                        float4 ea = *(const float4*)&ep[h*LLP + jj];
                        float4 eb = *(const float4*)&ep[h*LLP + jj + 4];
                        acc[h] += ea.x*z0 + ea.y*z1 + ea.z*z2 + ea.w*z3
                                + eb.x*z4 + eb.y*z5 + eb.z*z6 + eb.w*z7;
                    }
                }
                #pragma unroll
                for (int h = 0; h < HH; ++h) s_big[q4v*768 + h*64 + c] = acc[h];
            } else if (tid < 448) {
                // 2a: feat_node, hd = tid-256, 4 v loads in flight
                const int hd = tid - 256;
                const float* vb = vT + ((size_t)n*HD + hd)*LL;
                const float* ep = s_exp + (hd >> 4)*LLP;
                float a = 0.f;
                #pragma unroll 2
                for (int j4 = 0; j4 < 128; j4 += 4) {
                    float4 v0 = *(const float4*)(vb + j4*4);
                    float4 v1 = *(const float4*)(vb + j4*4 + 4);
                    float4 v2 = *(const float4*)(vb + j4*4 + 8);
                    float4 v3 = *(const float4*)(vb + j4*4 + 12);
                    float4 e0 = *(const float4*)(ep + j4*4);
                    float4 e1 = *(const float4*)(ep + j4*4 + 4);
                    float4 e2 = *(const float4*)(ep + j4*4 + 8);
                    float4 e3 = *(const float4*)(ep + j4*4 + 12);
                    a += v0.x*e0.x + v0.y*e0.y + v0.z*e0.z + v0.w*e0.w
                       + v1.x*e1.x + v1.y*e1.y + v1.z*e1.z + v1.w*e1.w
                       + v2.x*e2.x + v2.y*e2.y + v2.z*e2.z + v2.w*e2.w
                       + v3.x*e3.x + v3.y*e3.y + v3.z*e3.z + v3.w*e3.w;
                }
                s_f[768 + hd] = a * s_inv[hd >> 4];
            } else {
                // alpha . p_CB: 36 outputs on wave 7, p from LDS (was 512 global loads)
                const int o = tid - 448;
                if (o < 36) {
                    const int h = o / 3, ax = o - h*3;
                    const float* ep = s_exp + h*LLP;
                    float a = 0.f;
                    #pragma unroll 8
                    for (int j = 0; j < LL; ++j) a += ep[j] * s_p[j*3 + ax];
                    s_aggr[o] = a * s_inv[h];
                }
            }
        }
        __syncthreads();

        // ---- 2b reduce + phase 3 ----
        for (int o = tid; o < 768; o += 512)
            s_f[o] = (s_big[o] + s_big[768+o] + s_big[1536+o] + s_big[2304+o]) * s_inv[o >> 6];
        if (tid >= 500) {
            const int h = tid - 500;   // 0..11
            float m0 = s_aggr[h*3+0] - s_geo[3];
            float m1 = s_aggr[h*3+1] - s_geo[4];
            float m2 = s_aggr[h*3+2] - s_geo[5];
            const float* Rm = &s_geo[6];           // local_i = sum_j R[j][i]*m[j]
            float l0 = Rm[0]*m0 + Rm[3]*m1 + Rm[6]*m2;
            float l1 = Rm[1]*m0 + Rm[4]*m1 + Rm[7]*m2;
            float l2 = Rm[2]*m0 + Rm[5]*m1 + Rm[8]*m2;
            float dist = sqrtf(l0*l0 + l1*l1 + l2*l2);
            float idn = 1.0f/(dist + 1e-4f);
            s_f[960 + h*3+0] = l0; s_f[960 + h*3+1] = l1; s_f[960 + h*3+2] = l2;
            s_f[996 + h] = dist;
            s_f[1008 + h*3+0] = l0*idn; s_f[1008 + h*3+1] = l1*idn; s_f[1008 + h*3+2] = l2*idn;
        }
        __syncthreads();

        // ---- phase 4: output projection, 4 quarters per f ----
        {
            const int f = tid & 127, q4 = tid >> 7;
            const float* wr = Woutg + (size_t)f * FEAT;
            float acc = 0.f;
            #pragma unroll 4
            for (int kk = q4*4; kk < FEAT; kk += 16) {
                float4 fv  = *(const float4*)&s_f[kk];
                float4 wvv = *(const float4*)(wr + kk);
                acc += fv.x*wvv.x + fv.y*wvv.y + fv.z*wvv.z + fv.w*wvv.w;
            }
            s_big[q4*FF + f] = acc;
        }
        __syncthreads();
        if (tid < FF)
            s_y[tid] = s_x[tid] + boutg[tid]
                     + s_big[tid] + s_big[FF + tid] + s_big[2*FF + tid] + s_big[3*FF + tid];
    } else {
        if (tid < FF) s_y[tid] = s_x[tid];
    }
    __syncthreads();

    // ---- LayerNorm ----
    if (tid < 64) {
        float a = s_y[tid], b = s_y[tid + 64];
        float s1 = a + b, s2 = a*a + b*b;
        #pragma unroll
        for (int off = 32; off > 0; off >>= 1) {
            s1 += __shfl_xor(s1, off, 64);
            s2 += __shfl_xor(s2, off, 64);
        }
        if (tid == 0) { s_red[0] = s1; s_red[1] = s2; }
    }
    __syncthreads();
    if (tid < FF) {
        float mu  = s_red[0] * (1.0f/FF);
        float var = s_red[1] * (1.0f/FF) - mu*mu;
        float vv = (s_y[tid] - mu) * rsqrtf(fmaxf(var, 0.0f) + 1e-5f);
        vv = vv * lnwg[tid] + lnbg[tid];
        outg[(size_t)row*FF + tid] = vv;
    }
}

extern "C" void kernel_launch(void* const* d_in, const int* in_sizes, int n_in,
                              void* d_out, int out_size, void* d_ws, size_t ws_size,
                              hipStream_t stream) {
    const float* Rg    = (const float*)d_in[0];
    const float* tg    = (const float*)d_in[1];
    const float* pg    = (const float*)d_in[2];
    const float* xg    = (const float*)d_in[3];
    const float* zg    = (const float*)d_in[4];
    const int*   maskg = (const int*)d_in[5];
    const float* Wq    = (const float*)d_in[6];
    const float* Wk    = (const float*)d_in[7];
    const float* Wv    = (const float*)d_in[8];
    const float* Wpb   = (const float*)d_in[9];
    const float* gam   = (const float*)d_in[10];
    const float* Wout  = (const float*)d_in[11];
    const float* bout  = (const float*)d_in[12];
    const float* lnw   = (const float*)d_in[13];
    const float* lnb   = (const float*)d_in[14];
    float* outp = (float*)d_out;

    float* q_ws = (float*)d_ws;
    float* kT4  = q_ws + (size_t)NB*LL*HD;
    float* vT   = kT4  + (size_t)NB*LL*HD;
    int*   row_map = (int*)(vT + (size_t)NB*LL*HD);

    compact_kernel<<<1, NB*LL, 0, stream>>>(maskg, row_map);
    qkv_kernel<<<NB*LL/4, HD, 0, stream>>>(xg, Wq, Wk, Wv, q_ws, kT4, vT);
    attn_kernel<<<NB*LL, 512, 0, stream>>>(Rg, tg, pg, xg, zg, maskg,
                                           Wpb, gam, Wout, bout, lnw, lnb,
                                           q_ws, kT4, vT, row_map, outp);
}

// Round 4
// 272.086 us; speedup vs baseline: 1.2237x; 1.0839x over previous
//
#include <hip/hip_runtime.h>
#include <hip/hip_bf16.h>

constexpr int NB   = 2;
constexpr int LL   = 512;
constexpr int LLP  = 516;          // padded s_exp row stride (kills 4-way b128 conflicts)
constexpr int FF   = 128;
constexpr int CC   = 64;
constexpr int HH   = 12;
constexpr int DD   = 16;
constexpr int HD   = HH * DD;      // 192
constexpr int FEAT = HH*CC + HH*DD + HH*7;  // 1044
constexpr float INFV   = 100000.0f;
constexpr float SCALEF = 0.57735026918962576f;   // sqrt(1/3)
constexpr float SQ29H  = 0.23570226039551584f;   // sqrt(2/9)/2

// ---------------- kernel 0: active-row compaction ----------------
__global__ void compact_kernel(const int* __restrict__ maskg, int* __restrict__ row_map)
{
    const int tid = threadIdx.x;               // 1024 threads = NB*LL
    const int lane = tid & 63, wv = tid >> 6;  // 16 waves
    __shared__ int s_cnt[16];
    __shared__ int s_off[16];
    __shared__ int s_tot;
    const int m = maskg[tid] ? 1 : 0;
    unsigned long long b = __ballot(m);
    const int pre = __popcll(b & ((1ull << lane) - 1ull));
    if (lane == 0) s_cnt[wv] = __popcll(b);
    __syncthreads();
    if (tid == 0) {
        int s = 0;
        for (int w = 0; w < 16; ++w) { s_off[w] = s; s += s_cnt[w]; }
        s_tot = s;
    }
    __syncthreads();
    const int nact = s_off[wv] + pre;          // actives strictly before tid
    if (m) row_map[nact] = tid;
    else   row_map[s_tot + (tid - nact)] = tid;
}

// ---------------- kernel 1: q/k/v projections, 4 rows per block ----------------
__global__ __launch_bounds__(192) void qkv_kernel(
    const float* __restrict__ xg, const float* __restrict__ Wq,
    const float* __restrict__ Wk, const float* __restrict__ Wv,
    float* __restrict__ q_ws, float* __restrict__ kT4, float* __restrict__ vT)
{
    const int b = blockIdx.x;          // 256 blocks, rows b*4 .. b*4+3 (never straddle n)
    const int t = threadIdx.x;         // 192
    __shared__ __align__(16) float sx[4*FF];
    __shared__ __align__(16) float sw[3*HD*20];   // 45 KB

    for (int o = t; o < 4*FF; o += 192) sx[o] = xg[(size_t)b*4*FF + o];

    float aq[4] = {0.f,0.f,0.f,0.f};
    float ak[4] = {0.f,0.f,0.f,0.f};
    float av[4] = {0.f,0.f,0.f,0.f};

    for (int ft = 0; ft < 8; ++ft) {
        __syncthreads();
        #pragma unroll
        for (int m = 0; m < 3; ++m) {
            const float* W = (m == 0) ? Wq : ((m == 1) ? Wk : Wv);
            #pragma unroll
            for (int p = 0; p < 4; ++p) {
                const int r = (t >> 2) + 48*p, q = t & 3;
                float4 v = *(const float4*)(W + (size_t)r*FF + ft*16 + q*4);
                *(float4*)&sw[m*3840 + r*20 + q*4] = v;
            }
        }
        __syncthreads();
        const float* wq = &sw[0*3840 + t*20];
        const float* wk = &sw[1*3840 + t*20];
        const float* wv = &sw[2*3840 + t*20];
        #pragma unroll
        for (int f4 = 0; f4 < 4; ++f4) {
            float4 a  = *(const float4*)&wq[f4*4];
            float4 bq = *(const float4*)&wk[f4*4];
            float4 cq = *(const float4*)&wv[f4*4];
            #pragma unroll
            for (int r = 0; r < 4; ++r) {
                float4 xv = *(const float4*)&sx[r*FF + ft*16 + f4*4];   // broadcast
                aq[r] += xv.x*a.x  + xv.y*a.y  + xv.z*a.z  + xv.w*a.w;
                ak[r] += xv.x*bq.x + xv.y*bq.y + xv.z*bq.z + xv.w*bq.w;
                av[r] += xv.x*cq.x + xv.y*cq.y + xv.z*cq.z + xv.w*cq.w;
            }
        }
    }
    const int n = (b*4) >> 9, i0 = (b*4) & 511;
    #pragma unroll
    for (int r = 0; r < 4; ++r) {
        const int row = b*4 + r, i = i0 + r;
        q_ws[(size_t)row*HD + t] = aq[r];
        kT4[(((size_t)n*48 + (t >> 2))*LL + i)*4 + (t & 3)] = ak[r];
    }
    *(float4*)&vT[((size_t)n*HD + t)*LL + i0] = make_float4(av[0], av[1], av[2], av[3]);
}

// ---------------- kernel 2: fused attention (issue-pipe optimized) ----------------
// r4 changes vs r3:
//  - Wpb read from global with block-uniform indices -> scalar s_load path
//    (was 192 ds_read_b128 broadcasts per thread)
//  - per-head-sums phase folded into wave 7's P2 prologue; s_inv multiplies
//    deferred to P3 (saves one barrier + one all-wave phase)
//  - phase 4: quad-of-lanes per f -> Wout loads touch 16 lines/instr not 64;
//    shuffle-reduce replaces LDS partials + barrier
__global__ __launch_bounds__(512, 2) void attn_kernel(
    const float* __restrict__ Rg, const float* __restrict__ tg, const float* __restrict__ pg,
    const float* __restrict__ xg, const float* __restrict__ zg, const int* __restrict__ maskg,
    const float* __restrict__ Wpbg, const float* __restrict__ gammag,
    const float* __restrict__ Woutg, const float* __restrict__ boutg,
    const float* __restrict__ lnwg, const float* __restrict__ lnbg,
    const float* __restrict__ q_ws, const float* __restrict__ kT4, const float* __restrict__ vT,
    const int* __restrict__ row_map, float* __restrict__ outg)
{
    const int row = row_map[blockIdx.x];  // load-balanced: active rows first
    const int n = row >> 9;
    const int tid = threadIdx.x;

    __shared__ __align__(16) float s_exp[HH*LLP];  // 24.2 KB  exp(logits), h-major, padded
    __shared__ __align__(16) float s_big[4*768];   // 12 KB  2b partials
    __shared__ __align__(16) float s_p[3*LL];      // 6 KB   p_CB for this n
    __shared__ __align__(16) float s_q[HD];
    __shared__ __align__(16) float s_x[FF];
    __shared__ __align__(16) float s_y[FF];
    __shared__ __align__(16) float s_f[FEAT];
    __shared__ float s_aggr[36];
    __shared__ float s_inv[HH];
    __shared__ float s_coef[HH];
    __shared__ float s_geo[15];   // p_i[3], t[3], R[9]
    __shared__ float s_red[2];

    if (tid < FF) s_x[tid] = xg[(size_t)row*FF + tid];
    if (tid >= 128 && tid < 128 + HD) s_q[tid-128] = q_ws[(size_t)row*HD + (tid-128)];
    for (int o = tid; o < 3*LL; o += 512) s_p[o] = pg[(size_t)n*3*LL + o];
    if (tid >= 320 && tid < 332) {
        float g = gammag[tid-320];
        float gamma = log1pf(__expf(fminf(g, 80.0f)));   // softplus
        s_coef[tid-320] = -gamma * SQ29H;
    }
    if (tid >= 332 && tid < 335) s_geo[tid-332] = pg[(size_t)row*3 + (tid-332)];
    if (tid >= 335 && tid < 338) s_geo[3 + tid-335] = tg[(size_t)row*3 + (tid-335)];
    if (tid >= 338 && tid < 347) s_geo[6 + tid-338] = Rg[(size_t)row*9 + (tid-338)];
    const int mi = maskg[row];   // block-uniform
    __syncthreads();

    if (mi) {
        // ---- phase 1: exp(logits), one j per thread; Wpb via scalar loads ----
        {
            const int j = tid;
            float acc[HH];

            // z row -> 16 float4 regs, then FMA vs uniform (SGPR) Wpb
            const float* zr = zg + ((size_t)row*LL + j)*CC;
            float4 zv[16];
            #pragma unroll
            for (int c4 = 0; c4 < 16; ++c4) zv[c4] = ((const float4*)zr)[c4];
            #pragma unroll
            for (int h = 0; h < HH; ++h) {
                const float4* wh = (const float4*)(Wpbg + h*CC);   // block-uniform -> s_load
                float a = 0.f;
                #pragma unroll
                for (int c4 = 0; c4 < 16; ++c4) {
                    float4 w = wh[c4];
                    a += zv[c4].x*w.x + zv[c4].y*w.y + zv[c4].z*w.z + zv[c4].w*w.w;
                }
                acc[h] = a;
            }
            // q . k : kT4, 8 loads in flight per group
            const float* kb = kT4 + ((size_t)(n*48)*LL + j)*4;
            #pragma unroll
            for (int g = 0; g < 6; ++g) {
                float4 kv[8];
                #pragma unroll
                for (int u = 0; u < 8; ++u)
                    kv[u] = *(const float4*)(kb + (size_t)(g*8+u)*LL*4);
                #pragma unroll
                for (int u = 0; u < 8; ++u) {
                    const int hd4 = g*8+u;
                    float4 q4v = *(const float4*)&s_q[hd4*4];
                    acc[hd4 >> 2] += q4v.x*kv[u].x + q4v.y*kv[u].y + q4v.z*kv[u].z + q4v.w*kv[u].w;
                }
            }
            float e0 = s_geo[0]-s_p[j*3+0];
            float e1 = s_geo[1]-s_p[j*3+1];
            float e2 = s_geo[2]-s_p[j*3+2];
            float d2 = e0*e0 + e1*e1 + e2*e2;
            const float sub = maskg[n*LL + j] ? 0.0f : INFV;
            #pragma unroll
            for (int h = 0; h < HH; ++h) {
                float lg = (acc[h] + d2*s_coef[h]) * SCALEF - sub;
                s_exp[h*LLP + j] = __expf(fminf(lg, 80.0f));
            }
        }
        __syncthreads();

        // ---- phase 2: 2a / 2b / (sums + aggr) concurrent on disjoint waves ----
        // all s_inv multiplies deferred to phase 3.
        {
            const int wv = tid >> 6, lane = tid & 63;
            if (wv < 4) {
                // 2b: feat_p2n partials; 8 z loads in flight, float4 ep broadcasts
                const int c = lane, q4v = wv;
                float acc[HH];
                #pragma unroll
                for (int h = 0; h < HH; ++h) acc[h] = 0.f;
                const float* zb = zg + ((size_t)row*LL + q4v*128)*CC + c;
                const float* ep = s_exp + q4v*128;
                #pragma unroll 2
                for (int jj = 0; jj < 128; jj += 8) {
                    float z0 = zb[(size_t)(jj+0)*CC];
                    float z1 = zb[(size_t)(jj+1)*CC];
                    float z2 = zb[(size_t)(jj+2)*CC];
                    float z3 = zb[(size_t)(jj+3)*CC];
                    float z4 = zb[(size_t)(jj+4)*CC];
                    float z5 = zb[(size_t)(jj+5)*CC];
                    float z6 = zb[(size_t)(jj+6)*CC];
                    float z7 = zb[(size_t)(jj+7)*CC];
                    #pragma unroll
                    for (int h = 0; h < HH; ++h) {
                        float4 ea = *(const float4*)&ep[h*LLP + jj];
                        float4 eb = *(const float4*)&ep[h*LLP + jj + 4];
                        acc[h] += ea.x*z0 + ea.y*z1 + ea.z*z2 + ea.w*z3
                                + eb.x*z4 + eb.y*z5 + eb.z*z6 + eb.w*z7;
                    }
                }
                #pragma unroll
                for (int h = 0; h < HH; ++h) s_big[q4v*768 + h*64 + c] = acc[h];
            } else if (tid < 448) {
                // 2a: feat_node (raw, unscaled), hd = tid-256
                const int hd = tid - 256;
                const float* vb = vT + ((size_t)n*HD + hd)*LL;
                const float* ep = s_exp + (hd >> 4)*LLP;
                float a = 0.f;
                #pragma unroll 2
                for (int j4 = 0; j4 < 128; j4 += 4) {
                    float4 v0 = *(const float4*)(vb + j4*4);
                    float4 v1 = *(const float4*)(vb + j4*4 + 4);
                    float4 v2 = *(const float4*)(vb + j4*4 + 8);
                    float4 v3 = *(const float4*)(vb + j4*4 + 12);
                    float4 e0 = *(const float4*)(ep + j4*4);
                    float4 e1 = *(const float4*)(ep + j4*4 + 4);
                    float4 e2 = *(const float4*)(ep + j4*4 + 8);
                    float4 e3 = *(const float4*)(ep + j4*4 + 12);
                    a += v0.x*e0.x + v0.y*e0.y + v0.z*e0.z + v0.w*e0.w
                       + v1.x*e1.x + v1.y*e1.y + v1.z*e1.z + v1.w*e1.w
                       + v2.x*e2.x + v2.y*e2.y + v2.z*e2.z + v2.w*e2.w
                       + v3.x*e3.x + v3.y*e3.y + v3.z*e3.z + v3.w*e3.w;
                }
                s_f[768 + hd] = a;
            } else {
                // wave 7: per-head sums first (all 64 lanes), then raw aggr
                const int o = tid - 448;
                for (int h = 0; h < HH; ++h) {
                    float s = 0.f;
                    #pragma unroll
                    for (int r = 0; r < 8; ++r) s += s_exp[h*LLP + lane + (r<<6)];
                    #pragma unroll
                    for (int off = 32; off > 0; off >>= 1) s += __shfl_xor(s, off, 64);
                    if (lane == 0) s_inv[h] = 1.0f / fmaxf(s, 1e-30f);
                }
                if (o < 36) {
                    const int h = o / 3, ax = o - h*3;
                    const float* ep = s_exp + h*LLP;
                    float a = 0.f;
                    #pragma unroll 8
                    for (int j = 0; j < LL; ++j) a += ep[j] * s_p[j*3 + ax];
                    s_aggr[o] = a;   // raw; scaled in phase 3
                }
            }
        }
        __syncthreads();

        // ---- phase 3: apply s_inv + spatial features ----
        for (int o = tid; o < 960; o += 512) {
            if (o < 768)
                s_f[o] = (s_big[o] + s_big[768+o] + s_big[1536+o] + s_big[2304+o]) * s_inv[o >> 6];
            else
                s_f[o] = s_f[o] * s_inv[(o - 768) >> 4];
        }
        if (tid >= 500) {
            const int h = tid - 500;   // 0..11
            const float iv = s_inv[h];
            float m0 = s_aggr[h*3+0]*iv - s_geo[3];
            float m1 = s_aggr[h*3+1]*iv - s_geo[4];
            float m2 = s_aggr[h*3+2]*iv - s_geo[5];
            const float* Rm = &s_geo[6];           // local_i = sum_j R[j][i]*m[j]
            float l0 = Rm[0]*m0 + Rm[3]*m1 + Rm[6]*m2;
            float l1 = Rm[1]*m0 + Rm[4]*m1 + Rm[7]*m2;
            float l2 = Rm[2]*m0 + Rm[5]*m1 + Rm[8]*m2;
            float dist = sqrtf(l0*l0 + l1*l1 + l2*l2);
            float idn = 1.0f/(dist + 1e-4f);
            s_f[960 + h*3+0] = l0; s_f[960 + h*3+1] = l1; s_f[960 + h*3+2] = l2;
            s_f[996 + h] = dist;
            s_f[1008 + h*3+0] = l0*idn; s_f[1008 + h*3+1] = l1*idn; s_f[1008 + h*3+2] = l2*idn;
        }
        __syncthreads();

        // ---- phase 4: output projection; quad of lanes per f (16 lines/instr) ----
        {
            const int f = tid >> 2, q4 = tid & 3;
            const float* wr = Woutg + (size_t)f * FEAT;
            float acc = 0.f;
            #pragma unroll 4
            for (int kk = q4*4; kk < FEAT; kk += 16) {
                float4 fv  = *(const float4*)&s_f[kk];
                float4 wvv = *(const float4*)(wr + kk);
                acc += fv.x*wvv.x + fv.y*wvv.y + fv.z*wvv.z + fv.w*wvv.w;
            }
            acc += __shfl_xor(acc, 1, 64);
            acc += __shfl_xor(acc, 2, 64);
            if (q4 == 0) s_y[f] = s_x[f] + boutg[f] + acc;
        }
    } else {
        if (tid < FF) s_y[tid] = s_x[tid];
    }
    __syncthreads();

    // ---- LayerNorm ----
    if (tid < 64) {
        float a = s_y[tid], b = s_y[tid + 64];
        float s1 = a + b, s2 = a*a + b*b;
        #pragma unroll
        for (int off = 32; off > 0; off >>= 1) {
            s1 += __shfl_xor(s1, off, 64);
            s2 += __shfl_xor(s2, off, 64);
        }
        if (tid == 0) { s_red[0] = s1; s_red[1] = s2; }
    }
    __syncthreads();
    if (tid < FF) {
        float mu  = s_red[0] * (1.0f/FF);
        float var = s_red[1] * (1.0f/FF) - mu*mu;
        float vv = (s_y[tid] - mu) * rsqrtf(fmaxf(var, 0.0f) + 1e-5f);
        vv = vv * lnwg[tid] + lnbg[tid];
        outg[(size_t)row*FF + tid] = vv;
    }
}

extern "C" void kernel_launch(void* const* d_in, const int* in_sizes, int n_in,
                              void* d_out, int out_size, void* d_ws, size_t ws_size,
                              hipStream_t stream) {
    const float* Rg    = (const float*)d_in[0];
    const float* tg    = (const float*)d_in[1];
    const float* pg    = (const float*)d_in[2];
    const float* xg    = (const float*)d_in[3];
    const float* zg    = (const float*)d_in[4];
    const int*   maskg = (const int*)d_in[5];
    const float* Wq    = (const float*)d_in[6];
    const float* Wk    = (const float*)d_in[7];
    const float* Wv    = (const float*)d_in[8];
    const float* Wpb   = (const float*)d_in[9];
    const float* gam   = (const float*)d_in[10];
    const float* Wout  = (const float*)d_in[11];
    const float* bout  = (const float*)d_in[12];
    const float* lnw   = (const float*)d_in[13];
    const float* lnb   = (const float*)d_in[14];
    float* outp = (float*)d_out;

    float* q_ws = (float*)d_ws;
    float* kT4  = q_ws + (size_t)NB*LL*HD;
    float* vT   = kT4  + (size_t)NB*LL*HD;
    int*   row_map = (int*)(vT + (size_t)NB*LL*HD);

    compact_kernel<<<1, NB*LL, 0, stream>>>(maskg, row_map);
    qkv_kernel<<<NB*LL/4, HD, 0, stream>>>(xg, Wq, Wk, Wv, q_ws, kT4, vT);
    attn_kernel<<<NB*LL, 512, 0, stream>>>(Rg, tg, pg, xg, zg, maskg,
                                           Wpb, gam, Wout, bout, lnw, lnb,
                                           q_ws, kT4, vT, row_map, outp);
}

// Round 5
// 263.026 us; speedup vs baseline: 1.2659x; 1.0344x over previous
//
#include <hip/hip_runtime.h>
#include <hip/hip_bf16.h>

constexpr int NB   = 2;
constexpr int LL   = 512;
constexpr int LLP  = 516;          // padded s_exp row stride (kills 4-way b128 conflicts)
constexpr int FF   = 128;
constexpr int CC   = 64;
constexpr int HH   = 12;
constexpr int DD   = 16;
constexpr int HD   = HH * DD;      // 192
constexpr int FEAT = HH*CC + HH*DD + HH*7;  // 1044
constexpr float INFV   = 100000.0f;
constexpr float SCALEF = 0.57735026918962576f;   // sqrt(1/3)
constexpr float SQ29H  = 0.23570226039551584f;   // sqrt(2/9)/2

// ---------------- kernel 0: active-row compaction ----------------
__global__ void compact_kernel(const int* __restrict__ maskg, int* __restrict__ row_map)
{
    const int tid = threadIdx.x;               // 1024 threads = NB*LL
    const int lane = tid & 63, wv = tid >> 6;  // 16 waves
    __shared__ int s_cnt[16];
    __shared__ int s_off[16];
    __shared__ int s_tot;
    const int m = maskg[tid] ? 1 : 0;
    unsigned long long b = __ballot(m);
    const int pre = __popcll(b & ((1ull << lane) - 1ull));
    if (lane == 0) s_cnt[wv] = __popcll(b);
    __syncthreads();
    if (tid == 0) {
        int s = 0;
        for (int w = 0; w < 16; ++w) { s_off[w] = s; s += s_cnt[w]; }
        s_tot = s;
    }
    __syncthreads();
    const int nact = s_off[wv] + pre;          // actives strictly before tid
    if (m) row_map[nact] = tid;
    else   row_map[s_tot + (tid - nact)] = tid;
}

// ---------------- kernel 1: q/k/v projections, 4 rows per block ----------------
__global__ __launch_bounds__(192) void qkv_kernel(
    const float* __restrict__ xg, const float* __restrict__ Wq,
    const float* __restrict__ Wk, const float* __restrict__ Wv,
    float* __restrict__ q_ws, float* __restrict__ kT4, float* __restrict__ vT)
{
    const int b = blockIdx.x;          // 256 blocks, rows b*4 .. b*4+3 (never straddle n)
    const int t = threadIdx.x;         // 192
    __shared__ __align__(16) float sx[4*FF];
    __shared__ __align__(16) float sw[3*HD*20];   // 45 KB

    for (int o = t; o < 4*FF; o += 192) sx[o] = xg[(size_t)b*4*FF + o];

    float aq[4] = {0.f,0.f,0.f,0.f};
    float ak[4] = {0.f,0.f,0.f,0.f};
    float av[4] = {0.f,0.f,0.f,0.f};

    for (int ft = 0; ft < 8; ++ft) {
        __syncthreads();
        #pragma unroll
        for (int m = 0; m < 3; ++m) {
            const float* W = (m == 0) ? Wq : ((m == 1) ? Wk : Wv);
            #pragma unroll
            for (int p = 0; p < 4; ++p) {
                const int r = (t >> 2) + 48*p, q = t & 3;
                float4 v = *(const float4*)(W + (size_t)r*FF + ft*16 + q*4);
                *(float4*)&sw[m*3840 + r*20 + q*4] = v;
            }
        }
        __syncthreads();
        const float* wq = &sw[0*3840 + t*20];
        const float* wk = &sw[1*3840 + t*20];
        const float* wv = &sw[2*3840 + t*20];
        #pragma unroll
        for (int f4 = 0; f4 < 4; ++f4) {
            float4 a  = *(const float4*)&wq[f4*4];
            float4 bq = *(const float4*)&wk[f4*4];
            float4 cq = *(const float4*)&wv[f4*4];
            #pragma unroll
            for (int r = 0; r < 4; ++r) {
                float4 xv = *(const float4*)&sx[r*FF + ft*16 + f4*4];   // broadcast
                aq[r] += xv.x*a.x  + xv.y*a.y  + xv.z*a.z  + xv.w*a.w;
                ak[r] += xv.x*bq.x + xv.y*bq.y + xv.z*bq.z + xv.w*bq.w;
                av[r] += xv.x*cq.x + xv.y*cq.y + xv.z*cq.z + xv.w*cq.w;
            }
        }
    }
    const int n = (b*4) >> 9, i0 = (b*4) & 511;
    #pragma unroll
    for (int r = 0; r < 4; ++r) {
        const int row = b*4 + r, i = i0 + r;
        q_ws[(size_t)row*HD + t] = aq[r];
        kT4[(((size_t)n*48 + (t >> 2))*LL + i)*4 + (t & 3)] = ak[r];
    }
    *(float4*)&vT[((size_t)n*HD + t)*LL + i0] = make_float4(av[0], av[1], av[2], av[3]);
}

// ---------------- kernel 2: fused attention ----------------
// r5 change vs r4: phase 2a remapped to coalesced v reads.
//   was: lane = hd -> one instruction touches 64 rows 2KB apart = 64 cache
//        lines/instr (~24K line-requests per block, the same pathology the
//        r4 phase-4 remap removed for a -31us win)
//   now: lanes = 4 hd x 16 j-chunks -> 4 x 256B segments/instr (16x fewer),
//        dot finished by 16-lane shfl_xor tree.
__global__ __launch_bounds__(512, 2) void attn_kernel(
    const float* __restrict__ Rg, const float* __restrict__ tg, const float* __restrict__ pg,
    const float* __restrict__ xg, const float* __restrict__ zg, const int* __restrict__ maskg,
    const float* __restrict__ Wpbg, const float* __restrict__ gammag,
    const float* __restrict__ Woutg, const float* __restrict__ boutg,
    const float* __restrict__ lnwg, const float* __restrict__ lnbg,
    const float* __restrict__ q_ws, const float* __restrict__ kT4, const float* __restrict__ vT,
    const int* __restrict__ row_map, float* __restrict__ outg)
{
    const int row = row_map[blockIdx.x];  // load-balanced: active rows first
    const int n = row >> 9;
    const int tid = threadIdx.x;

    __shared__ __align__(16) float s_exp[HH*LLP];  // 24.2 KB  exp(logits), h-major, padded
    __shared__ __align__(16) float s_big[4*768];   // 12 KB  2b partials
    __shared__ __align__(16) float s_p[3*LL];      // 6 KB   p_CB for this n
    __shared__ __align__(16) float s_q[HD];
    __shared__ __align__(16) float s_x[FF];
    __shared__ __align__(16) float s_y[FF];
    __shared__ __align__(16) float s_f[FEAT];
    __shared__ float s_aggr[36];
    __shared__ float s_inv[HH];
    __shared__ float s_coef[HH];
    __shared__ float s_geo[15];   // p_i[3], t[3], R[9]
    __shared__ float s_red[2];

    if (tid < FF) s_x[tid] = xg[(size_t)row*FF + tid];
    if (tid >= 128 && tid < 128 + HD) s_q[tid-128] = q_ws[(size_t)row*HD + (tid-128)];
    for (int o = tid; o < 3*LL; o += 512) s_p[o] = pg[(size_t)n*3*LL + o];
    if (tid >= 320 && tid < 332) {
        float g = gammag[tid-320];
        float gamma = log1pf(__expf(fminf(g, 80.0f)));   // softplus
        s_coef[tid-320] = -gamma * SQ29H;
    }
    if (tid >= 332 && tid < 335) s_geo[tid-332] = pg[(size_t)row*3 + (tid-332)];
    if (tid >= 335 && tid < 338) s_geo[3 + tid-335] = tg[(size_t)row*3 + (tid-335)];
    if (tid >= 338 && tid < 347) s_geo[6 + tid-338] = Rg[(size_t)row*9 + (tid-338)];
    const int mi = maskg[row];   // block-uniform
    __syncthreads();

    if (mi) {
        // ---- phase 1: exp(logits), one j per thread; Wpb via scalar loads ----
        {
            const int j = tid;
            float acc[HH];

            // z row -> 16 float4 regs, then FMA vs uniform (SGPR) Wpb
            const float* zr = zg + ((size_t)row*LL + j)*CC;
            float4 zv[16];
            #pragma unroll
            for (int c4 = 0; c4 < 16; ++c4) zv[c4] = ((const float4*)zr)[c4];
            #pragma unroll
            for (int h = 0; h < HH; ++h) {
                const float4* wh = (const float4*)(Wpbg + h*CC);   // block-uniform -> s_load
                float a = 0.f;
                #pragma unroll
                for (int c4 = 0; c4 < 16; ++c4) {
                    float4 w = wh[c4];
                    a += zv[c4].x*w.x + zv[c4].y*w.y + zv[c4].z*w.z + zv[c4].w*w.w;
                }
                acc[h] = a;
            }
            // q . k : kT4, 8 loads in flight per group
            const float* kb = kT4 + ((size_t)(n*48)*LL + j)*4;
            #pragma unroll
            for (int g = 0; g < 6; ++g) {
                float4 kv[8];
                #pragma unroll
                for (int u = 0; u < 8; ++u)
                    kv[u] = *(const float4*)(kb + (size_t)(g*8+u)*LL*4);
                #pragma unroll
                for (int u = 0; u < 8; ++u) {
                    const int hd4 = g*8+u;
                    float4 q4v = *(const float4*)&s_q[hd4*4];
                    acc[hd4 >> 2] += q4v.x*kv[u].x + q4v.y*kv[u].y + q4v.z*kv[u].z + q4v.w*kv[u].w;
                }
            }
            float e0 = s_geo[0]-s_p[j*3+0];
            float e1 = s_geo[1]-s_p[j*3+1];
            float e2 = s_geo[2]-s_p[j*3+2];
            float d2 = e0*e0 + e1*e1 + e2*e2;
            const float sub = maskg[n*LL + j] ? 0.0f : INFV;
            #pragma unroll
            for (int h = 0; h < HH; ++h) {
                float lg = (acc[h] + d2*s_coef[h]) * SCALEF - sub;
                s_exp[h*LLP + j] = __expf(fminf(lg, 80.0f));
            }
        }
        __syncthreads();

        // ---- phase 2: 2a / 2b / (sums + aggr) concurrent on disjoint waves ----
        // all s_inv multiplies deferred to phase 3.
        {
            const int wv = tid >> 6, lane = tid & 63;
            if (wv < 4) {
                // 2b: feat_p2n partials; 8 z loads in flight, float4 ep broadcasts
                const int c = lane, q4v = wv;
                float acc[HH];
                #pragma unroll
                for (int h = 0; h < HH; ++h) acc[h] = 0.f;
                const float* zb = zg + ((size_t)row*LL + q4v*128)*CC + c;
                const float* ep = s_exp + q4v*128;
                #pragma unroll 2
                for (int jj = 0; jj < 128; jj += 8) {
                    float z0 = zb[(size_t)(jj+0)*CC];
                    float z1 = zb[(size_t)(jj+1)*CC];
                    float z2 = zb[(size_t)(jj+2)*CC];
                    float z3 = zb[(size_t)(jj+3)*CC];
                    float z4 = zb[(size_t)(jj+4)*CC];
                    float z5 = zb[(size_t)(jj+5)*CC];
                    float z6 = zb[(size_t)(jj+6)*CC];
                    float z7 = zb[(size_t)(jj+7)*CC];
                    #pragma unroll
                    for (int h = 0; h < HH; ++h) {
                        float4 ea = *(const float4*)&ep[h*LLP + jj];
                        float4 eb = *(const float4*)&ep[h*LLP + jj + 4];
                        acc[h] += ea.x*z0 + ea.y*z1 + ea.z*z2 + ea.w*z3
                                + eb.x*z4 + eb.y*z5 + eb.z*z6 + eb.w*z7;
                    }
                }
                #pragma unroll
                for (int h = 0; h < HH; ++h) s_big[q4v*768 + h*64 + c] = acc[h];
            } else if (tid < 448) {
                // 2a: feat_node; 4 hd rows x 16 j-chunks per instruction (coalesced)
                const int w = (tid >> 6) - 4;      // 0..2
                const int hsub = lane >> 4;        // 0..3
                const int jj = lane & 15;          // 0..15
                const int wbase = w * 64;
                #pragma unroll 2
                for (int g = 0; g < 16; ++g) {
                    const int hd = wbase + g*4 + hsub;
                    const float* vb = vT + ((size_t)n*HD + hd)*LL;
                    const float* ep = s_exp + (hd >> 4)*LLP;
                    float a = 0.f;
                    #pragma unroll
                    for (int t8 = 0; t8 < 8; ++t8) {
                        float4 vv = *(const float4*)(vb + (jj + 16*t8)*4);
                        float4 ev = *(const float4*)(ep + (jj + 16*t8)*4);
                        a += vv.x*ev.x + vv.y*ev.y + vv.z*ev.z + vv.w*ev.w;
                    }
                    a += __shfl_xor(a, 1, 64);
                    a += __shfl_xor(a, 2, 64);
                    a += __shfl_xor(a, 4, 64);
                    a += __shfl_xor(a, 8, 64);
                    if (jj == 0) s_f[768 + hd] = a;   // raw; scaled in phase 3
                }
            } else {
                // wave 7: per-head sums first (all 64 lanes), then raw aggr
                const int o = tid - 448;
                for (int h = 0; h < HH; ++h) {
                    float s = 0.f;
                    #pragma unroll
                    for (int r = 0; r < 8; ++r) s += s_exp[h*LLP + lane + (r<<6)];
                    #pragma unroll
                    for (int off = 32; off > 0; off >>= 1) s += __shfl_xor(s, off, 64);
                    if (lane == 0) s_inv[h] = 1.0f / fmaxf(s, 1e-30f);
                }
                if (o < 36) {
                    const int h = o / 3, ax = o - h*3;
                    const float* ep = s_exp + h*LLP;
                    float a = 0.f;
                    #pragma unroll 8
                    for (int j = 0; j < LL; ++j) a += ep[j] * s_p[j*3 + ax];
                    s_aggr[o] = a;   // raw; scaled in phase 3
                }
            }
        }
        __syncthreads();

        // ---- phase 3: apply s_inv + spatial features ----
        for (int o = tid; o < 960; o += 512) {
            if (o < 768)
                s_f[o] = (s_big[o] + s_big[768+o] + s_big[1536+o] + s_big[2304+o]) * s_inv[o >> 6];
            else
                s_f[o] = s_f[o] * s_inv[(o - 768) >> 4];
        }
        if (tid >= 500) {
            const int h = tid - 500;   // 0..11
            const float iv = s_inv[h];
            float m0 = s_aggr[h*3+0]*iv - s_geo[3];
            float m1 = s_aggr[h*3+1]*iv - s_geo[4];
            float m2 = s_aggr[h*3+2]*iv - s_geo[5];
            const float* Rm = &s_geo[6];           // local_i = sum_j R[j][i]*m[j]
            float l0 = Rm[0]*m0 + Rm[3]*m1 + Rm[6]*m2;
            float l1 = Rm[1]*m0 + Rm[4]*m1 + Rm[7]*m2;
            float l2 = Rm[2]*m0 + Rm[5]*m1 + Rm[8]*m2;
            float dist = sqrtf(l0*l0 + l1*l1 + l2*l2);
            float idn = 1.0f/(dist + 1e-4f);
            s_f[960 + h*3+0] = l0; s_f[960 + h*3+1] = l1; s_f[960 + h*3+2] = l2;
            s_f[996 + h] = dist;
            s_f[1008 + h*3+0] = l0*idn; s_f[1008 + h*3+1] = l1*idn; s_f[1008 + h*3+2] = l2*idn;
        }
        __syncthreads();

        // ---- phase 4: output projection; quad of lanes per f (16 lines/instr) ----
        {
            const int f = tid >> 2, q4 = tid & 3;
            const float* wr = Woutg + (size_t)f * FEAT;
            float acc = 0.f;
            #pragma unroll 4
            for (int kk = q4*4; kk < FEAT; kk += 16) {
                float4 fv  = *(const float4*)&s_f[kk];
                float4 wvv = *(const float4*)(wr + kk);
                acc += fv.x*wvv.x + fv.y*wvv.y + fv.z*wvv.z + fv.w*wvv.w;
            }
            acc += __shfl_xor(acc, 1, 64);
            acc += __shfl_xor(acc, 2, 64);
            if (q4 == 0) s_y[f] = s_x[f] + boutg[f] + acc;
        }
    } else {
        if (tid < FF) s_y[tid] = s_x[tid];
    }
    __syncthreads();

    // ---- LayerNorm ----
    if (tid < 64) {
        float a = s_y[tid], b = s_y[tid + 64];
        float s1 = a + b, s2 = a*a + b*b;
        #pragma unroll
        for (int off = 32; off > 0; off >>= 1) {
            s1 += __shfl_xor(s1, off, 64);
            s2 += __shfl_xor(s2, off, 64);
        }
        if (tid == 0) { s_red[0] = s1; s_red[1] = s2; }
    }
    __syncthreads();
    if (tid < FF) {
        float mu  = s_red[0] * (1.0f/FF);
        float var = s_red[1] * (1.0f/FF) - mu*mu;
        float vv = (s_y[tid] - mu) * rsqrtf(fmaxf(var, 0.0f) + 1e-5f);
        vv = vv * lnwg[tid] + lnbg[tid];
        outg[(size_t)row*FF + tid] = vv;
    }
}

extern "C" void kernel_launch(void* const* d_in, const int* in_sizes, int n_in,
                              void* d_out, int out_size, void* d_ws, size_t ws_size,
                              hipStream_t stream) {
    const float* Rg    = (const float*)d_in[0];
    const float* tg    = (const float*)d_in[1];
    const float* pg    = (const float*)d_in[2];
    const float* xg    = (const float*)d_in[3];
    const float* zg    = (const float*)d_in[4];
    const int*   maskg = (const int*)d_in[5];
    const float* Wq    = (const float*)d_in[6];
    const float* Wk    = (const float*)d_in[7];
    const float* Wv    = (const float*)d_in[8];
    const float* Wpb   = (const float*)d_in[9];
    const float* gam   = (const float*)d_in[10];
    const float* Wout  = (const float*)d_in[11];
    const float* bout  = (const float*)d_in[12];
    const float* lnw   = (const float*)d_in[13];
    const float* lnb   = (const float*)d_in[14];
    float* outp = (float*)d_out;

    float* q_ws = (float*)d_ws;
    float* kT4  = q_ws + (size_t)NB*LL*HD;
    float* vT   = kT4  + (size_t)NB*LL*HD;
    int*   row_map = (int*)(vT + (size_t)NB*LL*HD);

    compact_kernel<<<1, NB*LL, 0, stream>>>(maskg, row_map);
    qkv_kernel<<<NB*LL/4, HD, 0, stream>>>(xg, Wq, Wk, Wv, q_ws, kT4, vT);
    attn_kernel<<<NB*LL, 512, 0, stream>>>(Rg, tg, pg, xg, zg, maskg,
                                           Wpb, gam, Wout, bout, lnw, lnb,
                                           q_ws, kT4, vT, row_map, outp);
}